// Round 4
// baseline (172.092 us; speedup 1.0000x reference)
//
#include <hip/hip_runtime.h>
#include <math.h>
#include <type_traits>

#define BB 2
#define SS 2048
#define DD 64
#define HH 12
// Q pre-scaled by 1/ln2 in qkv; exp(s-16) == exp2(s' - 16/ln2)
#define C2FIX 23.083120654223414f

typedef _Float16 v8h __attribute__((ext_vector_type(8)));
typedef short    v8s __attribute__((ext_vector_type(8)));
typedef float    v4f __attribute__((ext_vector_type(4)));
typedef unsigned int v2u __attribute__((ext_vector_type(2)));

__device__ __forceinline__ unsigned short f2bf(float f) {
    unsigned u = __float_as_uint(f);
    u += 0x7FFF + ((u >> 16) & 1);          // RTN-even
    return (unsigned short)(u >> 16);
}

__device__ __forceinline__ void async16(const void* g, void* l) {
    __builtin_amdgcn_global_load_lds(
        (const __attribute__((address_space(1))) unsigned int*)g,
        (__attribute__((address_space(3))) unsigned int*)l, 16, 0, 0);
}

// ---------------------------------------------------------------------------
// Kernel 0: prep. x -> x16 fp16; [Wq|Wk|Wv] -> W16 fp16 B-layout [2304][64];
// Wo -> WoT fp16 [64][768].  (exact R12/R15 baseline)
// ---------------------------------------------------------------------------
__global__ __launch_bounds__(256) void prep_kernel(
    const float* __restrict__ x,
    const float* __restrict__ Wq, const float* __restrict__ Wk,
    const float* __restrict__ Wv, const float* __restrict__ Wo,
    _Float16* __restrict__ x16, _Float16* __restrict__ W16,
    _Float16* __restrict__ WoT)
{
    const int idx = blockIdx.x * 256 + threadIdx.x;
    if (idx < 262144) {
        x16[idx] = (_Float16)x[idx];
    } else if (idx < 262144 + 147456) {
        const int t = idx - 262144;
        const int k = t / 2304, c = t % 2304;        // coalesced read over c
        const int mat = c / 768, cc = c % 768;
        const float* W = (mat == 0) ? Wq : (mat == 1) ? Wk : Wv;
        W16[c * 64 + k] = (_Float16)W[k * 768 + cc];
    } else {
        const int e = idx - 262144 - 147456;         // < 49152
        WoT[(e & 63) * 768 + (e >> 6)] = (_Float16)Wo[e];
    }
}

// ---------------------------------------------------------------------------
// Kernel 1: QKV projection via MFMA (exact R12/R15 baseline). Q pre-scaled.
// ---------------------------------------------------------------------------
__global__ __launch_bounds__(256) void qkv_kernel(
    const _Float16* __restrict__ x16, const _Float16* __restrict__ W16,
    const float* __restrict__ bq, const float* __restrict__ bk,
    const float* __restrict__ bv,
    _Float16* __restrict__ Q16, _Float16* __restrict__ K16,
    unsigned short* __restrict__ VT)
{
    const int r0  = blockIdx.x * 64;
    const int c0g = blockIdx.y * 64;
    const int mat = c0g / 768, cc0 = c0g % 768;
    const int h   = cc0 >> 6;
    const int b   = r0 >> 11, s0 = r0 & 2047;

    const int wave = threadIdx.x >> 6, lane = threadIdx.x & 63;
    const int llow = lane & 15, quad = lane >> 4;
    const int rowbase = r0 + 16 * wave;

    const float* bias = (mat == 0) ? bq : (mat == 1) ? bk : bv;

    v8h a0 = *(const v8h*)(x16 + (size_t)(rowbase + llow) * 64 + quad * 8);
    v8h a1 = *(const v8h*)(x16 + (size_t)(rowbase + llow) * 64 + 32 + quad * 8);

    v4f acc[4];
    float bv4[4];
#pragma unroll
    for (int nb = 0; nb < 4; nb++) {
        const int col = c0g + 16 * nb + llow;
        v8h b0 = *(const v8h*)(W16 + (size_t)col * 64 + quad * 8);
        v8h b1 = *(const v8h*)(W16 + (size_t)col * 64 + 32 + quad * 8);
        v4f a = (v4f){0.f, 0.f, 0.f, 0.f};
        a = __builtin_amdgcn_mfma_f32_16x16x32_f16(a0, b0, a, 0, 0, 0);
        a = __builtin_amdgcn_mfma_f32_16x16x32_f16(a1, b1, a, 0, 0, 0);
        acc[nb] = a;
        bv4[nb] = bias[cc0 + 16 * nb + llow];
    }

    const int bh = b * HH + h;
    if (mat == 0) {                                  // Q: pre-scale by 1/ln2
#pragma unroll
        for (int nb = 0; nb < 4; nb++)
#pragma unroll
            for (int r = 0; r < 4; r++) {
                const int s = s0 + 16 * wave + quad * 4 + r;
                Q16[((size_t)bh * SS + s) * 64 + 16 * nb + llow] =
                    (_Float16)((acc[nb][r] + bv4[nb]) * 1.4426950408889634f);
            }
    } else if (mat == 1) {
#pragma unroll
        for (int nb = 0; nb < 4; nb++)
#pragma unroll
            for (int r = 0; r < 4; r++) {
                const int s = s0 + 16 * wave + quad * 4 + r;
                K16[((size_t)bh * SS + s) * 64 + 16 * nb + llow] =
                    (_Float16)(acc[nb][r] + bv4[nb]);
            }
    } else {
#pragma unroll
        for (int nb = 0; nb < 4; nb++) {
            const int d = 16 * nb + llow;
            const int s = s0 + 16 * wave + quad * 4;     // 4 consecutive s
            unsigned short p0 = f2bf(acc[nb][0] + bv4[nb]);
            unsigned short p1 = f2bf(acc[nb][1] + bv4[nb]);
            unsigned short p2 = f2bf(acc[nb][2] + bv4[nb]);
            unsigned short p3 = f2bf(acc[nb][3] + bv4[nb]);
            v2u pk = (v2u){(unsigned)p0 | ((unsigned)p1 << 16),
                           (unsigned)p2 | ((unsigned)p3 << 16)};
            *(v2u*)&VT[((size_t)bh * 64 + d) * SS + s] = pk;
        }
    }
}

// ---------------------------------------------------------------------------
// Kernel 2: MFMA flash attention. R16 single change-group: V is NO LONGER
// LDS-staged (guide common-mistake #7: V^T tile is 8 KB, L1-resident across
// the block's 4 waves; VT per head 256 KB, L2-resident). V^T is read
// directly from global into registers at tile start — QK^T + softmax +
// Pl round-trip hide the latency. K stays DMA-staged (needed at tile
// start, wants the 1-tile-ahead prefetch). LDS per tile-unit 112->64 KB;
// LDS footprint 40->24 KB (occupancy can rise past 4 blocks/CU if VGPR
// permits). Keeps R15's MFMA row-sum ones-trick + v_perm pair-pack.
// Address check: old swizzled Vl read retrieved key-octet `quad` of row
// rv => direct VT[(16nb+llow)*SS + kt + 8*quad] (+32 hi) is identical data.
// ---------------------------------------------------------------------------
__global__ __launch_bounds__(256, 4) void attn_kernel(
    const _Float16* __restrict__ Q16, const _Float16* __restrict__ K16,
    const unsigned short* __restrict__ VTg, _Float16* __restrict__ O16)
{
    __shared__ __align__(16) _Float16       Kl[2][64 * 64];   // [key][d], xor-swizzled
    __shared__ __align__(16) unsigned short Pl[4][16 * 64];   // [row][key], octet-swizzled

    const int bh    = blockIdx.y;
    const int qtile = (int)((blockIdx.x + 11 * blockIdx.y) & 31);   // balance swizzle
    const int qBase = qtile * 64;
    const int wave  = threadIdx.x >> 6;
    const int lane  = threadIdx.x & 63;
    const int llow  = lane & 15;
    const int quad  = lane >> 4;
    const int q0    = qBase + 16 * wave;

    const _Float16*       Kp = K16 + (size_t)bh * SS * 64;
    const unsigned short* Vp = VTg + (size_t)bh * 64 * SS;

    const _Float16* Qp = Q16 + ((size_t)bh * SS + q0) * 64;
    v8h qa0 = *(const v8h*)(Qp + llow * 64 + quad * 8);
    v8h qa1 = *(const v8h*)(Qp + llow * 64 + 32 + quad * 8);

    v4f o[4];
    v4f ls = (v4f){0.f, 0.f, 0.f, 0.f};             // row sums via MFMA
    const short one_bf = (short)0x3F80;              // bf16 1.0
    const v8s vones = (v8s){one_bf, one_bf, one_bf, one_bf,
                            one_bf, one_bf, one_bf, one_bf};
#pragma unroll
    for (int nb = 0; nb < 4; nb++) o[nb] = (v4f){0.f, 0.f, 0.f, 0.f};

    const int nt = qtile + 1;       // 64-key tiles needed
    const int qrow = q0 + llow;
    const int sw = llow & 7;

    // prefetch K tile 0 into buf 0 (wave-uniform base + lane*16 dest, DMA rule)
#pragma unroll
    for (int rep = 0; rep < 2; rep++) {
        int c = rep * 256 + threadIdx.x;
        int row = c >> 3, g = (c & 7) ^ (row & 7);
        async16(Kp + (size_t)row * 64 + g * 8, &Kl[0][(rep * 256 + wave * 64) * 8]);
    }

    auto tile_body = [&](int t, auto masked_c) {
        constexpr bool MASKED = decltype(masked_c)::value;
        __syncthreads();                 // drains this tile's K-DMA
        if (t + 1 < nt) {                // prefetch AFTER barrier -> overlaps compute
            const int ktn = (t + 1) * 64, bufn = (t + 1) & 1;
#pragma unroll
            for (int rep = 0; rep < 2; rep++) {
                int c = rep * 256 + threadIdx.x;
                int row = c >> 3, g = (c & 7) ^ (row & 7);
                async16(Kp + (size_t)(ktn + row) * 64 + g * 8,
                        &Kl[bufn][(rep * 256 + wave * 64) * 8]);
            }
        }
        const int buf = t & 1, kt = t * 64;

        // ---- V^T direct from global (L1/L2-resident): issue EARLY so the
        //      QK^T + softmax + Pl round-trip hide the latency ----
        v8s vv0[4], vv1[4];
#pragma unroll
        for (int nb = 0; nb < 4; nb++) {
            const unsigned short* vrow =
                Vp + (size_t)(16 * nb + llow) * SS + kt + 8 * quad;
            vv0[nb] = *(const v8s*)vrow;          // keys kt+8q .. +7
            vv1[nb] = *(const v8s*)(vrow + 32);   // keys kt+32+8q .. +7
        }

        // ---- S^T = K·Q^T over all 64 keys: 4 col-blocks of 16 ----
        v4f sc[4];
#pragma unroll
        for (int cb = 0; cb < 4; cb++) {
            const int rk = 16 * cb + llow;                       // rk&7 == sw
            v8h k0 = *(const v8h*)&Kl[buf][rk * 64 + ((quad ^ sw)) * 8];
            v8h k1 = *(const v8h*)&Kl[buf][rk * 64 + (((4 + quad) ^ sw)) * 8];
            v4f a2 = (v4f){0.f, 0.f, 0.f, 0.f};
            a2 = __builtin_amdgcn_mfma_f32_16x16x32_f16(k0, qa0, a2, 0, 0, 0);
            a2 = __builtin_amdgcn_mfma_f32_16x16x32_f16(k1, qa1, a2, 0, 0, 0);
            sc[cb] = a2;  // C: col=llow=q-row, row=quad*4+r=key offset
        }

        // ---- quirky mask + exp2; pack P in A-order, octet-swizzled ----
#pragma unroll
        for (int cb = 0; cb < 4; cb++) {
            const int kbase = kt + 16 * cb + quad * 4;
            unsigned dw[2];
#pragma unroll
            for (int h2 = 0; h2 < 2; h2++) {
                float pv2[2];
#pragma unroll
                for (int j2 = 0; j2 < 2; j2++) {
                    const int r = h2 * 2 + j2;
                    const float sv = sc[cb][r];
                    const float e  = __builtin_amdgcn_exp2f(sv - C2FIX);
                    float p;
                    if constexpr (MASKED)
                        p = (kbase + r <= qrow && sv != 0.f) ? e : 0.f;
                    else
                        p = (sv != 0.f) ? e : 0.f;   // tril-zero quirk only
                    pv2[j2] = p;
                }
                // bf16-trunc pair pack: one v_perm_b32 (bytes lo.2,lo.3,hi.2,hi.3)
                dw[h2] = __builtin_amdgcn_perm(__float_as_uint(pv2[1]),
                                               __float_as_uint(pv2[0]),
                                               0x07060302u);
            }
            // natural pos 16cb+4quad -> octet (2cb+(quad>>1)) ^ sw, half (quad&1)*4
            *(v2u*)&Pl[wave][llow * 64 + (((2 * cb + (quad >> 1)) ^ sw) * 8)
                             + (quad & 1) * 4] = (v2u){dw[0], dw[1]};
        }

        // ---- P A-frags: 2x b128, octet-swizzled (same wave: lgkm only) ----
        v8s pa0 = *(const v8s*)&Pl[wave][llow * 64 + ((quad ^ sw) * 8)];
        v8s pa1 = *(const v8s*)&Pl[wave][llow * 64 + (((4 + quad) ^ sw) * 8)];

        // ---- row sums on the MFMA pipe: ls += P · ones ----
        ls = __builtin_amdgcn_mfma_f32_16x16x32_bf16(pa0, vones, ls, 0, 0, 0);
        ls = __builtin_amdgcn_mfma_f32_16x16x32_bf16(pa1, vones, ls, 0, 0, 0);

        // ---- PV over all 64 keys (bf16): A=P, B=V^T (registers) ----
#pragma unroll
        for (int nb = 0; nb < 4; nb++) {
            o[nb] = __builtin_amdgcn_mfma_f32_16x16x32_bf16(pa0, vv0[nb], o[nb], 0, 0, 0);
            o[nb] = __builtin_amdgcn_mfma_f32_16x16x32_bf16(pa1, vv1[nb], o[nb], 0, 0, 0);
        }
    };

    for (int t = 0; t < nt - 1; t++) tile_body(t, std::false_type{});
    tile_body(nt - 1, std::true_type{});            // diagonal tile: causal mask

    // ---- epilogue: ls[r] IS the full row sum for row quad*4+r (no shuffles)
    float ir[4];
#pragma unroll
    for (int r = 0; r < 4; r++)
        ir[r] = 1.0f / ls[r];
    _Float16* Op = O16 + ((size_t)bh * SS + q0) * 64;
#pragma unroll
    for (int nb = 0; nb < 4; nb++)
#pragma unroll
        for (int r = 0; r < 4; r++)
            Op[(quad * 4 + r) * 64 + 16 * nb + llow] = (_Float16)(o[nb][r] * ir[r]);
}

// ---------------------------------------------------------------------------
// Kernel 3: output projection via MFMA (unchanged).
// ---------------------------------------------------------------------------
__global__ __launch_bounds__(256) void out_kernel(
    const _Float16* __restrict__ O16, const _Float16* __restrict__ WoT,
    const float* __restrict__ bo, float* __restrict__ out)
{
    __shared__ __align__(16) float red[4][16][66];
    const int r0   = blockIdx.x * 16;
    const int wave = threadIdx.x >> 6, lane = threadIdx.x & 63;
    const int llow = lane & 15, quad = lane >> 4;
    const int b = r0 >> 11, s = r0 & 2047;

    v4f acc[4];
#pragma unroll
    for (int cb = 0; cb < 4; cb++) acc[cb] = (v4f){0.f, 0.f, 0.f, 0.f};

#pragma unroll
    for (int i = 0; i < 6; i++) {
        const int kb = wave * 6 + i;                // 0..23
        const int h = kb >> 1, dseg = (kb & 1) * 32;
        v8h af = *(const v8h*)(O16 + ((size_t)(b * HH + h) * SS + s + llow) * 64 + dseg + quad * 8);
#pragma unroll
        for (int cb = 0; cb < 4; cb++) {
            v8h bf = *(const v8h*)(WoT + (size_t)(16 * cb + llow) * 768 + kb * 32 + quad * 8);
            acc[cb] = __builtin_amdgcn_mfma_f32_16x16x32_f16(af, bf, acc[cb], 0, 0, 0);
        }
    }

#pragma unroll
    for (int cb = 0; cb < 4; cb++)
#pragma unroll
        for (int r = 0; r < 4; r++)
            red[wave][quad * 4 + r][16 * cb + llow] = acc[cb][r];
    __syncthreads();

    const int col = threadIdx.x & 63, rr = threadIdx.x >> 6;
    const float bias = bo[col];
    for (int i = rr; i < 16; i += 4) {
        float sum = red[0][i][col] + red[1][i][col] + red[2][i][col] + red[3][i][col] + bias;
        out[(size_t)(r0 + i) * 64 + col] = sum;
    }
}

// ---------------------------------------------------------------------------
extern "C" void kernel_launch(void* const* d_in, const int* in_sizes, int n_in,
                              void* d_out, int out_size, void* d_ws, size_t ws_size,
                              hipStream_t stream)
{
    const float* x  = (const float*)d_in[0];
    const float* Wq = (const float*)d_in[1];
    const float* bq = (const float*)d_in[2];
    const float* Wk = (const float*)d_in[3];
    const float* bk = (const float*)d_in[4];
    const float* Wv = (const float*)d_in[5];
    const float* bv = (const float*)d_in[6];
    const float* Wo = (const float*)d_in[7];
    const float* bo = (const float*)d_in[8];
    float* out = (float*)d_out;

    char* w = (char*)d_ws;
    const size_t MB = 1024 * 1024;
    _Float16*       x16 = (_Float16*)(w);                 // 512 KB
    _Float16*       W16 = (_Float16*)(w + 512 * 1024);    // 288 KB
    _Float16*       WoT = (_Float16*)(w + 832 * 1024);    // 96 KB
    _Float16*       Q16 = (_Float16*)(w + 1 * MB);        // 6 MB each
    _Float16*       K16 = (_Float16*)(w + 7 * MB);
    unsigned short* VT  = (unsigned short*)(w + 13 * MB);
    _Float16*       O16 = (_Float16*)(w + 19 * MB);

    prep_kernel<<<1792, 256, 0, stream>>>(x, Wq, Wk, Wv, Wo, x16, W16, WoT);
    qkv_kernel<<<dim3(64, 36), 256, 0, stream>>>(x16, W16, bq, bk, bv, Q16, K16, VT);
    attn_kernel<<<dim3(32, BB * HH), 256, 0, stream>>>(Q16, K16, VT, O16);
    out_kernel<<<(BB * SS) / 16, 256, 0, stream>>>(O16, WoT, bo, out);
}

// Round 5
// 139.537 us; speedup vs baseline: 1.2333x; 1.2333x over previous
//
#include <hip/hip_runtime.h>
#include <math.h>
#include <type_traits>

#define BB 2
#define SS 2048
#define DD 64
#define HH 12
// Q pre-scaled by 1/ln2 in qkv; exp(s-16) == exp2(s' - 16/ln2)
#define C2FIX 23.083120654223414f
#define NITEMS (BB * HH * 32)   // 768 (bh, qtile) work items

typedef _Float16 v8h __attribute__((ext_vector_type(8)));
typedef short    v8s __attribute__((ext_vector_type(8)));
typedef float    v4f __attribute__((ext_vector_type(4)));
typedef unsigned int v2u __attribute__((ext_vector_type(2)));

__device__ __forceinline__ unsigned short f2bf(float f) {
    unsigned u = __float_as_uint(f);
    u += 0x7FFF + ((u >> 16) & 1);          // RTN-even
    return (unsigned short)(u >> 16);
}

__device__ __forceinline__ void async16(const void* g, void* l) {
    __builtin_amdgcn_global_load_lds(
        (const __attribute__((address_space(1))) unsigned int*)g,
        (__attribute__((address_space(3))) unsigned int*)l, 16, 0, 0);
}

// ---------------------------------------------------------------------------
// Kernel 0: prep. x -> x16 fp16; [Wq|Wk|Wv] -> W16 fp16 B-layout [2304][64];
// Wo -> WoT fp16 [64][768]. R17: also zeroes the attn work-queue counter.
// ---------------------------------------------------------------------------
__global__ __launch_bounds__(256) void prep_kernel(
    const float* __restrict__ x,
    const float* __restrict__ Wq, const float* __restrict__ Wk,
    const float* __restrict__ Wv, const float* __restrict__ Wo,
    _Float16* __restrict__ x16, _Float16* __restrict__ W16,
    _Float16* __restrict__ WoT, unsigned* __restrict__ ctr)
{
    const int idx = blockIdx.x * 256 + threadIdx.x;
    if (idx == 0) ctr[0] = 0;                        // work-queue init
    if (idx < 262144) {
        x16[idx] = (_Float16)x[idx];
    } else if (idx < 262144 + 147456) {
        const int t = idx - 262144;
        const int k = t / 2304, c = t % 2304;        // coalesced read over c
        const int mat = c / 768, cc = c % 768;
        const float* W = (mat == 0) ? Wq : (mat == 1) ? Wk : Wv;
        W16[c * 64 + k] = (_Float16)W[k * 768 + cc];
    } else {
        const int e = idx - 262144 - 147456;         // < 49152
        WoT[(e & 63) * 768 + (e >> 6)] = (_Float16)Wo[e];
    }
}

// ---------------------------------------------------------------------------
// Kernel 1: QKV projection via MFMA (exact R12/R15 baseline). Q pre-scaled.
// ---------------------------------------------------------------------------
__global__ __launch_bounds__(256) void qkv_kernel(
    const _Float16* __restrict__ x16, const _Float16* __restrict__ W16,
    const float* __restrict__ bq, const float* __restrict__ bk,
    const float* __restrict__ bv,
    _Float16* __restrict__ Q16, _Float16* __restrict__ K16,
    unsigned short* __restrict__ VT)
{
    const int r0  = blockIdx.x * 64;
    const int c0g = blockIdx.y * 64;
    const int mat = c0g / 768, cc0 = c0g % 768;
    const int h   = cc0 >> 6;
    const int b   = r0 >> 11, s0 = r0 & 2047;

    const int wave = threadIdx.x >> 6, lane = threadIdx.x & 63;
    const int llow = lane & 15, quad = lane >> 4;
    const int rowbase = r0 + 16 * wave;

    const float* bias = (mat == 0) ? bq : (mat == 1) ? bk : bv;

    v8h a0 = *(const v8h*)(x16 + (size_t)(rowbase + llow) * 64 + quad * 8);
    v8h a1 = *(const v8h*)(x16 + (size_t)(rowbase + llow) * 64 + 32 + quad * 8);

    v4f acc[4];
    float bv4[4];
#pragma unroll
    for (int nb = 0; nb < 4; nb++) {
        const int col = c0g + 16 * nb + llow;
        v8h b0 = *(const v8h*)(W16 + (size_t)col * 64 + quad * 8);
        v8h b1 = *(const v8h*)(W16 + (size_t)col * 64 + 32 + quad * 8);
        v4f a = (v4f){0.f, 0.f, 0.f, 0.f};
        a = __builtin_amdgcn_mfma_f32_16x16x32_f16(a0, b0, a, 0, 0, 0);
        a = __builtin_amdgcn_mfma_f32_16x16x32_f16(a1, b1, a, 0, 0, 0);
        acc[nb] = a;
        bv4[nb] = bias[cc0 + 16 * nb + llow];
    }

    const int bh = b * HH + h;
    if (mat == 0) {                                  // Q: pre-scale by 1/ln2
#pragma unroll
        for (int nb = 0; nb < 4; nb++)
#pragma unroll
            for (int r = 0; r < 4; r++) {
                const int s = s0 + 16 * wave + quad * 4 + r;
                Q16[((size_t)bh * SS + s) * 64 + 16 * nb + llow] =
                    (_Float16)((acc[nb][r] + bv4[nb]) * 1.4426950408889634f);
            }
    } else if (mat == 1) {
#pragma unroll
        for (int nb = 0; nb < 4; nb++)
#pragma unroll
            for (int r = 0; r < 4; r++) {
                const int s = s0 + 16 * wave + quad * 4 + r;
                K16[((size_t)bh * SS + s) * 64 + 16 * nb + llow] =
                    (_Float16)(acc[nb][r] + bv4[nb]);
            }
    } else {
#pragma unroll
        for (int nb = 0; nb < 4; nb++) {
            const int d = 16 * nb + llow;
            const int s = s0 + 16 * wave + quad * 4;     // 4 consecutive s
            unsigned short p0 = f2bf(acc[nb][0] + bv4[nb]);
            unsigned short p1 = f2bf(acc[nb][1] + bv4[nb]);
            unsigned short p2 = f2bf(acc[nb][2] + bv4[nb]);
            unsigned short p3 = f2bf(acc[nb][3] + bv4[nb]);
            v2u pk = (v2u){(unsigned)p0 | ((unsigned)p1 << 16),
                           (unsigned)p2 | ((unsigned)p3 << 16)};
            *(v2u*)&VT[((size_t)bh * 64 + d) * SS + s] = pk;
        }
    }
}

// ---------------------------------------------------------------------------
// Kernel 2: MFMA flash attention. R17 = exact R15 tile internals (K AND V
// DMA-staged — R16's V-direct-read thrashed L2: 46.9 MB HBM fetch, 80 us,
// reverted) + dynamic work queue. Blocks grab (bh,qtile) items from a
// global atomic counter in DESCENDING-qtile order (LPT): per-CU work
// self-balances to ~49.5 tile-units regardless of the dispatcher's
// block->CU mapping (R13's static remap failed precisely because that
// mapping is unknown). One atomicAdd per item; s_item handoff is guarded
// by the loop-top barrier + >=1 tile_body barrier per item.
// ---------------------------------------------------------------------------
__global__ __launch_bounds__(256, 4) void attn_kernel(
    const _Float16* __restrict__ Q16, const _Float16* __restrict__ K16,
    const unsigned short* __restrict__ VTg, _Float16* __restrict__ O16,
    unsigned* __restrict__ ctr)
{
    __shared__ __align__(16) _Float16       Kl[2][64 * 64];   // [key][d], xor-swizzled
    __shared__ __align__(16) unsigned short Vl[2][64 * 64];   // [d][key], xor-swizzled
    __shared__ __align__(16) unsigned short Pl[4][16 * 64];   // [row][key], octet-swizzled
    __shared__ int s_item;

    const int wave  = threadIdx.x >> 6;
    const int lane  = threadIdx.x & 63;
    const int llow  = lane & 15;
    const int quad  = lane >> 4;
    const int sw    = llow & 7;

    const short one_bf = (short)0x3F80;              // bf16 1.0
    const v8s vones = (v8s){one_bf, one_bf, one_bf, one_bf,
                            one_bf, one_bf, one_bf, one_bf};

    for (;;) {
        if (threadIdx.x == 0) s_item = (int)atomicAdd(ctr, 1u);
        __syncthreads();                 // also fences previous item's LDS use
        const int item = s_item;
        if (item >= NITEMS) break;

        // LPT order: largest qtile first
        const int qtile = 31 - (item / (BB * HH));
        const int bh    = item % (BB * HH);
        const int q0    = qtile * 64 + 16 * wave;

        const _Float16*       Kp = K16 + (size_t)bh * SS * 64;
        const unsigned short* Vp = VTg + (size_t)bh * 64 * SS;

        const _Float16* Qp = Q16 + ((size_t)bh * SS + q0) * 64;
        v8h qa0 = *(const v8h*)(Qp + llow * 64 + quad * 8);
        v8h qa1 = *(const v8h*)(Qp + llow * 64 + 32 + quad * 8);

        v4f o[4];
        v4f ls = (v4f){0.f, 0.f, 0.f, 0.f};         // row sums via MFMA
#pragma unroll
        for (int nb = 0; nb < 4; nb++) o[nb] = (v4f){0.f, 0.f, 0.f, 0.f};

        const int nt = qtile + 1;       // 64-key tiles needed
        const int qrow = q0 + llow;

        // prefetch tile 0 into buf 0 (wave-uniform base + lane*16 dest)
#pragma unroll
        for (int rep = 0; rep < 2; rep++) {
            int c = rep * 256 + threadIdx.x;
            int row = c >> 3, g = (c & 7) ^ (row & 7);
            async16(Kp + (size_t)row * 64 + g * 8, &Kl[0][(rep * 256 + wave * 64) * 8]);
            async16(Vp + (size_t)row * SS + g * 8, &Vl[0][(rep * 256 + wave * 64) * 8]);
        }

        auto tile_body = [&](int t, auto masked_c) {
            constexpr bool MASKED = decltype(masked_c)::value;
            __syncthreads();                 // drains this tile's DMA
            if (t + 1 < nt) {                // prefetch AFTER barrier -> overlaps compute
                const int ktn = (t + 1) * 64, bufn = (t + 1) & 1;
#pragma unroll
                for (int rep = 0; rep < 2; rep++) {
                    int c = rep * 256 + threadIdx.x;
                    int row = c >> 3, g = (c & 7) ^ (row & 7);
                    async16(Kp + (size_t)(ktn + row) * 64 + g * 8,
                            &Kl[bufn][(rep * 256 + wave * 64) * 8]);
                    async16(Vp + (size_t)row * SS + ktn + g * 8,
                            &Vl[bufn][(rep * 256 + wave * 64) * 8]);
                }
            }
            const int buf = t & 1, kt = t * 64;

            // ---- S^T = K·Q^T over all 64 keys: 4 col-blocks of 16 ----
            v4f sc[4];
#pragma unroll
            for (int cb = 0; cb < 4; cb++) {
                const int rk = 16 * cb + llow;                       // rk&7 == sw
                v8h k0 = *(const v8h*)&Kl[buf][rk * 64 + ((quad ^ sw)) * 8];
                v8h k1 = *(const v8h*)&Kl[buf][rk * 64 + (((4 + quad) ^ sw)) * 8];
                v4f a2 = (v4f){0.f, 0.f, 0.f, 0.f};
                a2 = __builtin_amdgcn_mfma_f32_16x16x32_f16(k0, qa0, a2, 0, 0, 0);
                a2 = __builtin_amdgcn_mfma_f32_16x16x32_f16(k1, qa1, a2, 0, 0, 0);
                sc[cb] = a2;  // C: col=llow=q-row, row=quad*4+r=key offset
            }

            // ---- quirky mask + exp2; pack P in A-order, octet-swizzled ----
#pragma unroll
            for (int cb = 0; cb < 4; cb++) {
                const int kbase = kt + 16 * cb + quad * 4;
                unsigned dw[2];
#pragma unroll
                for (int h2 = 0; h2 < 2; h2++) {
                    float pv2[2];
#pragma unroll
                    for (int j2 = 0; j2 < 2; j2++) {
                        const int r = h2 * 2 + j2;
                        const float sv = sc[cb][r];
                        const float e  = __builtin_amdgcn_exp2f(sv - C2FIX);
                        float p;
                        if constexpr (MASKED)
                            p = (kbase + r <= qrow && sv != 0.f) ? e : 0.f;
                        else
                            p = (sv != 0.f) ? e : 0.f;   // tril-zero quirk only
                        pv2[j2] = p;
                    }
                    // bf16-trunc pair pack: one v_perm_b32
                    dw[h2] = __builtin_amdgcn_perm(__float_as_uint(pv2[1]),
                                                   __float_as_uint(pv2[0]),
                                                   0x07060302u);
                }
                // natural pos 16cb+4quad -> octet (2cb+(quad>>1)) ^ sw, half (quad&1)*4
                *(v2u*)&Pl[wave][llow * 64 + (((2 * cb + (quad >> 1)) ^ sw) * 8)
                                 + (quad & 1) * 4] = (v2u){dw[0], dw[1]};
            }

            // ---- P A-frags: 2x b128, octet-swizzled (same wave: lgkm only) ----
            v8s pa0 = *(const v8s*)&Pl[wave][llow * 64 + ((quad ^ sw) * 8)];
            v8s pa1 = *(const v8s*)&Pl[wave][llow * 64 + (((4 + quad) ^ sw) * 8)];

            // ---- row sums on the MFMA pipe: ls += P · ones ----
            ls = __builtin_amdgcn_mfma_f32_16x16x32_bf16(pa0, vones, ls, 0, 0, 0);
            ls = __builtin_amdgcn_mfma_f32_16x16x32_bf16(pa1, vones, ls, 0, 0, 0);

            // ---- PV over all 64 keys (bf16): A=P, B=V^T ----
#pragma unroll
            for (int nb = 0; nb < 4; nb++) {
                const int rv = 16 * nb + llow;                       // rv&7 == sw
                v8s vv0 = *(const v8s*)&Vl[buf][rv * 64 + ((quad ^ sw)) * 8];
                v8s vv1 = *(const v8s*)&Vl[buf][rv * 64 + (((4 + quad) ^ sw)) * 8];
                o[nb] = __builtin_amdgcn_mfma_f32_16x16x32_bf16(pa0, vv0, o[nb], 0, 0, 0);
                o[nb] = __builtin_amdgcn_mfma_f32_16x16x32_bf16(pa1, vv1, o[nb], 0, 0, 0);
            }
        };

        for (int t = 0; t < nt - 1; t++) tile_body(t, std::false_type{});
        tile_body(nt - 1, std::true_type{});        // diagonal tile: causal mask

        // ---- epilogue: ls[r] IS the full row sum for row quad*4+r ----
        float ir[4];
#pragma unroll
        for (int r = 0; r < 4; r++)
            ir[r] = 1.0f / ls[r];
        _Float16* Op = O16 + ((size_t)bh * SS + q0) * 64;
#pragma unroll
        for (int nb = 0; nb < 4; nb++)
#pragma unroll
            for (int r = 0; r < 4; r++)
                Op[(quad * 4 + r) * 64 + 16 * nb + llow] = (_Float16)(o[nb][r] * ir[r]);
    }
}

// ---------------------------------------------------------------------------
// Kernel 3: output projection via MFMA (unchanged).
// ---------------------------------------------------------------------------
__global__ __launch_bounds__(256) void out_kernel(
    const _Float16* __restrict__ O16, const _Float16* __restrict__ WoT,
    const float* __restrict__ bo, float* __restrict__ out)
{
    __shared__ __align__(16) float red[4][16][66];
    const int r0   = blockIdx.x * 16;
    const int wave = threadIdx.x >> 6, lane = threadIdx.x & 63;
    const int llow = lane & 15, quad = lane >> 4;
    const int b = r0 >> 11, s = r0 & 2047;

    v4f acc[4];
#pragma unroll
    for (int cb = 0; cb < 4; cb++) acc[cb] = (v4f){0.f, 0.f, 0.f, 0.f};

#pragma unroll
    for (int i = 0; i < 6; i++) {
        const int kb = wave * 6 + i;                // 0..23
        const int h = kb >> 1, dseg = (kb & 1) * 32;
        v8h af = *(const v8h*)(O16 + ((size_t)(b * HH + h) * SS + s + llow) * 64 + dseg + quad * 8);
#pragma unroll
        for (int cb = 0; cb < 4; cb++) {
            v8h bf = *(const v8h*)(WoT + (size_t)(16 * cb + llow) * 768 + kb * 32 + quad * 8);
            acc[cb] = __builtin_amdgcn_mfma_f32_16x16x32_f16(af, bf, acc[cb], 0, 0, 0);
        }
    }

#pragma unroll
    for (int cb = 0; cb < 4; cb++)
#pragma unroll
        for (int r = 0; r < 4; r++)
            red[wave][quad * 4 + r][16 * cb + llow] = acc[cb][r];
    __syncthreads();

    const int col = threadIdx.x & 63, rr = threadIdx.x >> 6;
    const float bias = bo[col];
    for (int i = rr; i < 16; i += 4) {
        float sum = red[0][i][col] + red[1][i][col] + red[2][i][col] + red[3][i][col] + bias;
        out[(size_t)(r0 + i) * 64 + col] = sum;
    }
}

// ---------------------------------------------------------------------------
extern "C" void kernel_launch(void* const* d_in, const int* in_sizes, int n_in,
                              void* d_out, int out_size, void* d_ws, size_t ws_size,
                              hipStream_t stream)
{
    const float* x  = (const float*)d_in[0];
    const float* Wq = (const float*)d_in[1];
    const float* bq = (const float*)d_in[2];
    const float* Wk = (const float*)d_in[3];
    const float* bk = (const float*)d_in[4];
    const float* Wv = (const float*)d_in[5];
    const float* bv = (const float*)d_in[6];
    const float* Wo = (const float*)d_in[7];
    const float* bo = (const float*)d_in[8];
    float* out = (float*)d_out;

    char* w = (char*)d_ws;
    const size_t MB = 1024 * 1024;
    _Float16*       x16 = (_Float16*)(w);                 // 512 KB
    _Float16*       W16 = (_Float16*)(w + 512 * 1024);    // 288 KB
    _Float16*       WoT = (_Float16*)(w + 832 * 1024);    // 96 KB
    _Float16*       Q16 = (_Float16*)(w + 1 * MB);        // 6 MB each
    _Float16*       K16 = (_Float16*)(w + 7 * MB);
    unsigned short* VT  = (unsigned short*)(w + 13 * MB);
    _Float16*       O16 = (_Float16*)(w + 19 * MB);
    unsigned*       ctr = (unsigned*)(w + 25 * MB);       // work-queue counter

    prep_kernel<<<1792, 256, 0, stream>>>(x, Wq, Wk, Wv, Wo, x16, W16, WoT, ctr);
    qkv_kernel<<<dim3(64, 36), 256, 0, stream>>>(x16, W16, bq, bk, bv, Q16, K16, VT);
    attn_kernel<<<NITEMS, 256, 0, stream>>>(Q16, K16, VT, O16, ctr);
    out_kernel<<<(BB * SS) / 16, 256, 0, stream>>>(O16, WoT, bo, out);
}

// Round 7
// 136.450 us; speedup vs baseline: 1.2612x; 1.0226x over previous
//
#include <hip/hip_runtime.h>
#include <math.h>
#include <type_traits>

#define BB 2
#define SS 2048
#define DD 64
#define HH 12
// Q pre-scaled by 1/ln2 in qkv; exp(s-16) == exp2(s' - 16/ln2)
#define C2FIX 23.083120654223414f

typedef _Float16 v8h __attribute__((ext_vector_type(8)));
typedef short    v8s __attribute__((ext_vector_type(8)));
typedef float    v4f __attribute__((ext_vector_type(4)));
typedef unsigned int v2u __attribute__((ext_vector_type(2)));

__device__ __forceinline__ unsigned short f2bf(float f) {
    unsigned u = __float_as_uint(f);
    u += 0x7FFF + ((u >> 16) & 1);          // RTN-even
    return (unsigned short)(u >> 16);
}

__device__ __forceinline__ void async16(const void* g, void* l) {
    __builtin_amdgcn_global_load_lds(
        (const __attribute__((address_space(1))) unsigned int*)g,
        (__attribute__((address_space(3))) unsigned int*)l, 16, 0, 0);
}

// ---------------------------------------------------------------------------
// Kernel 0: prep. x -> x16 fp16; [Wq|Wk|Wv] -> W16 fp16 B-layout [2304][64];
// Wo -> WoT fp16 [64][768].  (exact R15 baseline)
// ---------------------------------------------------------------------------
__global__ __launch_bounds__(256) void prep_kernel(
    const float* __restrict__ x,
    const float* __restrict__ Wq, const float* __restrict__ Wk,
    const float* __restrict__ Wv, const float* __restrict__ Wo,
    _Float16* __restrict__ x16, _Float16* __restrict__ W16,
    _Float16* __restrict__ WoT)
{
    const int idx = blockIdx.x * 256 + threadIdx.x;
    if (idx < 262144) {
        x16[idx] = (_Float16)x[idx];
    } else if (idx < 262144 + 147456) {
        const int t = idx - 262144;
        const int k = t / 2304, c = t % 2304;        // coalesced read over c
        const int mat = c / 768, cc = c % 768;
        const float* W = (mat == 0) ? Wq : (mat == 1) ? Wk : Wv;
        W16[c * 64 + k] = (_Float16)W[k * 768 + cc];
    } else {
        const int e = idx - 262144 - 147456;         // < 49152
        WoT[(e & 63) * 768 + (e >> 6)] = (_Float16)Wo[e];
    }
}

// ---------------------------------------------------------------------------
// Kernel 1: QKV projection via MFMA (exact R12/R15 baseline). Q pre-scaled.
// ---------------------------------------------------------------------------
__global__ __launch_bounds__(256) void qkv_kernel(
    const _Float16* __restrict__ x16, const _Float16* __restrict__ W16,
    const float* __restrict__ bq, const float* __restrict__ bk,
    const float* __restrict__ bv,
    _Float16* __restrict__ Q16, _Float16* __restrict__ K16,
    unsigned short* __restrict__ VT)
{
    const int r0  = blockIdx.x * 64;
    const int c0g = blockIdx.y * 64;
    const int mat = c0g / 768, cc0 = c0g % 768;
    const int h   = cc0 >> 6;
    const int b   = r0 >> 11, s0 = r0 & 2047;

    const int wave = threadIdx.x >> 6, lane = threadIdx.x & 63;
    const int llow = lane & 15, quad = lane >> 4;
    const int rowbase = r0 + 16 * wave;

    const float* bias = (mat == 0) ? bq : (mat == 1) ? bk : bv;

    v8h a0 = *(const v8h*)(x16 + (size_t)(rowbase + llow) * 64 + quad * 8);
    v8h a1 = *(const v8h*)(x16 + (size_t)(rowbase + llow) * 64 + 32 + quad * 8);

    v4f acc[4];
    float bv4[4];
#pragma unroll
    for (int nb = 0; nb < 4; nb++) {
        const int col = c0g + 16 * nb + llow;
        v8h b0 = *(const v8h*)(W16 + (size_t)col * 64 + quad * 8);
        v8h b1 = *(const v8h*)(W16 + (size_t)col * 64 + 32 + quad * 8);
        v4f a = (v4f){0.f, 0.f, 0.f, 0.f};
        a = __builtin_amdgcn_mfma_f32_16x16x32_f16(a0, b0, a, 0, 0, 0);
        a = __builtin_amdgcn_mfma_f32_16x16x32_f16(a1, b1, a, 0, 0, 0);
        acc[nb] = a;
        bv4[nb] = bias[cc0 + 16 * nb + llow];
    }

    const int bh = b * HH + h;
    if (mat == 0) {                                  // Q: pre-scale by 1/ln2
#pragma unroll
        for (int nb = 0; nb < 4; nb++)
#pragma unroll
            for (int r = 0; r < 4; r++) {
                const int s = s0 + 16 * wave + quad * 4 + r;
                Q16[((size_t)bh * SS + s) * 64 + 16 * nb + llow] =
                    (_Float16)((acc[nb][r] + bv4[nb]) * 1.4426950408889634f);
            }
    } else if (mat == 1) {
#pragma unroll
        for (int nb = 0; nb < 4; nb++)
#pragma unroll
            for (int r = 0; r < 4; r++) {
                const int s = s0 + 16 * wave + quad * 4 + r;
                K16[((size_t)bh * SS + s) * 64 + 16 * nb + llow] =
                    (_Float16)(acc[nb][r] + bv4[nb]);
            }
    } else {
#pragma unroll
        for (int nb = 0; nb < 4; nb++) {
            const int d = 16 * nb + llow;
            const int s = s0 + 16 * wave + quad * 4;     // 4 consecutive s
            unsigned short p0 = f2bf(acc[nb][0] + bv4[nb]);
            unsigned short p1 = f2bf(acc[nb][1] + bv4[nb]);
            unsigned short p2 = f2bf(acc[nb][2] + bv4[nb]);
            unsigned short p3 = f2bf(acc[nb][3] + bv4[nb]);
            v2u pk = (v2u){(unsigned)p0 | ((unsigned)p1 << 16),
                           (unsigned)p2 | ((unsigned)p3 << 16)};
            *(v2u*)&VT[((size_t)bh * 64 + d) * SS + s] = pk;
        }
    }
}

// ---------------------------------------------------------------------------
// Kernel 2: MFMA flash attention, R19 = R18 split-K wave groups + the
// MISSING BARRIER. R18's NaN root cause: after the final round, group-B
// waves wrote merge partials into Kl[1]/Vl[1] while OTHER B waves were
// still reading the full buffers in their final QK^T/PV (oShare spans both
// of B's K buffers). Fix: __syncthreads() between the rounds loop and the
// merge writes. Design recap: fixed-C exp2 softmax has no running max ->
// partial (o, ls) over disjoint key sets merge by pure addition. Waves 0-3
// (group A) do even 64-key tiles, waves 4-7 (B) odd tiles, own K/V dbuf
// each; rounds = ceil(nt/2), one barrier per round -> longest serial chain
// 32 -> 16 tile-steps. LDS 80 KB -> 2 blocks/CU (16 waves/CU).
// ---------------------------------------------------------------------------
__global__ __launch_bounds__(512, 4) void attn_kernel(
    const _Float16* __restrict__ Q16, const _Float16* __restrict__ K16,
    const unsigned short* __restrict__ VTg, _Float16* __restrict__ O16)
{
    __shared__ __align__(16) _Float16       Kl[2][2][64 * 64];  // [grp][buf][key][d]
    __shared__ __align__(16) unsigned short Vl[2][2][64 * 64];  // [grp][buf][d][key]
    __shared__ __align__(16) unsigned short Pl[8][16 * 64];     // [wave][row][key]

    const int bh    = blockIdx.y;
    const int qtile = (int)((blockIdx.x + 11 * blockIdx.y) & 31);   // balance swizzle
    const int qBase = qtile * 64;
    const int wave  = threadIdx.x >> 6;      // 0..7
    const int grp   = wave >> 2;             // 0 = even tiles, 1 = odd tiles
    const int gw    = wave & 3;              // wave within group
    const int gtid  = threadIdx.x & 255;     // thread within group
    const int lane  = threadIdx.x & 63;
    const int llow  = lane & 15;
    const int quad  = lane >> 4;
    const int q0    = qBase + 16 * gw;
    const int sw    = llow & 7;

    const _Float16*       Kp = K16 + (size_t)bh * SS * 64;
    const unsigned short* Vp = VTg + (size_t)bh * 64 * SS;

    const _Float16* Qp = Q16 + ((size_t)bh * SS + q0) * 64;
    v8h qa0 = *(const v8h*)(Qp + llow * 64 + quad * 8);
    v8h qa1 = *(const v8h*)(Qp + llow * 64 + 32 + quad * 8);

    v4f o[4];
    v4f ls = (v4f){0.f, 0.f, 0.f, 0.f};             // row sums via MFMA
    const short one_bf = (short)0x3F80;              // bf16 1.0
    const v8s vones = (v8s){one_bf, one_bf, one_bf, one_bf,
                            one_bf, one_bf, one_bf, one_bf};
#pragma unroll
    for (int nb = 0; nb < 4; nb++) o[nb] = (v4f){0.f, 0.f, 0.f, 0.f};

    const int nt = qtile + 1;        // total 64-key tiles
    const int R  = (nt + 1) >> 1;    // rounds (group A: ceil, B: floor)
    const int qrow = q0 + llow;

    // stage one 64-key tile for MY group into buf b (wave-uniform dest + lane*16)
    auto stage = [&](int kt, int b) {
#pragma unroll
        for (int rep = 0; rep < 2; rep++) {
            int c = rep * 256 + gtid;
            int row = c >> 3, g = (c & 7) ^ (row & 7);
            async16(Kp + (size_t)(kt + row) * 64 + g * 8,
                    &Kl[grp][b][(rep * 256 + gw * 64) * 8]);
            async16(Vp + (size_t)row * SS + kt + g * 8,
                    &Vl[grp][b][(rep * 256 + gw * 64) * 8]);
        }
    };

    // initial prefetch: A tile 0; B tile 1 (if it exists)
    if (grp == 0)      stage(0, 0);
    else if (nt > 1)   stage(64, 0);

    auto round_body = [&](int r, auto masked_c) {
        constexpr bool MASKED = decltype(masked_c)::value;
        __syncthreads();                 // drains this round's DMA (both groups)
        {   // prefetch round r+1 for my group
            const int tn = 2 * (r + 1) + grp;
            if (tn < nt) stage(tn * 64, (r + 1) & 1);
        }
        const int t = 2 * r + grp;
        if (t >= nt) return;             // B idle in final round when nt odd
        const int buf = r & 1, kt = t * 64;

        // ---- S^T = K·Q^T over all 64 keys: 4 col-blocks of 16 ----
        v4f sc[4];
#pragma unroll
        for (int cb = 0; cb < 4; cb++) {
            const int rk = 16 * cb + llow;                       // rk&7 == sw
            v8h k0 = *(const v8h*)&Kl[grp][buf][rk * 64 + ((quad ^ sw)) * 8];
            v8h k1 = *(const v8h*)&Kl[grp][buf][rk * 64 + (((4 + quad) ^ sw)) * 8];
            v4f a2 = (v4f){0.f, 0.f, 0.f, 0.f};
            a2 = __builtin_amdgcn_mfma_f32_16x16x32_f16(k0, qa0, a2, 0, 0, 0);
            a2 = __builtin_amdgcn_mfma_f32_16x16x32_f16(k1, qa1, a2, 0, 0, 0);
            sc[cb] = a2;  // C: col=llow=q-row, row=quad*4+rr=key offset
        }

        // ---- quirky mask + exp2; pack P in A-order, octet-swizzled ----
#pragma unroll
        for (int cb = 0; cb < 4; cb++) {
            const int kbase = kt + 16 * cb + quad * 4;
            unsigned dw[2];
#pragma unroll
            for (int h2 = 0; h2 < 2; h2++) {
                float pv2[2];
#pragma unroll
                for (int j2 = 0; j2 < 2; j2++) {
                    const int rr = h2 * 2 + j2;
                    const float sv = sc[cb][rr];
                    const float e  = __builtin_amdgcn_exp2f(sv - C2FIX);
                    float p;
                    if constexpr (MASKED)
                        p = (kbase + rr <= qrow && sv != 0.f) ? e : 0.f;
                    else
                        p = (sv != 0.f) ? e : 0.f;   // tril-zero quirk only
                    pv2[j2] = p;
                }
                // bf16-trunc pair pack: one v_perm_b32
                dw[h2] = __builtin_amdgcn_perm(__float_as_uint(pv2[1]),
                                               __float_as_uint(pv2[0]),
                                               0x07060302u);
            }
            // natural pos 16cb+4quad -> octet (2cb+(quad>>1)) ^ sw, half (quad&1)*4
            *(v2u*)&Pl[wave][llow * 64 + (((2 * cb + (quad >> 1)) ^ sw) * 8)
                             + (quad & 1) * 4] = (v2u){dw[0], dw[1]};
        }

        // ---- P A-frags: 2x b128, octet-swizzled (same wave: lgkm only) ----
        v8s pa0 = *(const v8s*)&Pl[wave][llow * 64 + ((quad ^ sw) * 8)];
        v8s pa1 = *(const v8s*)&Pl[wave][llow * 64 + (((4 + quad) ^ sw) * 8)];

        // ---- row sums on the MFMA pipe: ls += P · ones ----
        ls = __builtin_amdgcn_mfma_f32_16x16x32_bf16(pa0, vones, ls, 0, 0, 0);
        ls = __builtin_amdgcn_mfma_f32_16x16x32_bf16(pa1, vones, ls, 0, 0, 0);

        // ---- PV over all 64 keys (bf16): A=P, B=V^T ----
#pragma unroll
        for (int nb = 0; nb < 4; nb++) {
            const int rv = 16 * nb + llow;                       // rv&7 == sw
            v8s vv0 = *(const v8s*)&Vl[grp][buf][rv * 64 + ((quad ^ sw)) * 8];
            v8s vv1 = *(const v8s*)&Vl[grp][buf][rv * 64 + (((4 + quad) ^ sw)) * 8];
            o[nb] = __builtin_amdgcn_mfma_f32_16x16x32_bf16(pa0, vv0, o[nb], 0, 0, 0);
            o[nb] = __builtin_amdgcn_mfma_f32_16x16x32_bf16(pa1, vv1, o[nb], 0, 0, 0);
        }
    };

    for (int r = 0; r < R - 1; r++) round_body(r, std::false_type{});
    round_body(R - 1, std::true_type{});    // final round: masked (exact for both)

    // ---- R19 FIX: all waves must finish reading K/V LDS before B reuses
    //      those buffers as the merge scratch (R18 raced here -> NaN) ----
    __syncthreads();

    // ---- merge: B writes partials into its own (now idle) K/V buffers ----
    float* oShare  = (float*)&Kl[1][0][0];   // 4096 floats: [nb][gw*64+lane] v4f
    float* lsShare = (float*)&Vl[1][0][0];   // 1024 floats
    if (grp == 1) {
        const int sl = (gw * 64 + lane) * 4;
#pragma unroll
        for (int nb = 0; nb < 4; nb++)
            *(v4f*)&oShare[nb * 1024 + sl] = o[nb];
        *(v4f*)&lsShare[sl] = ls;
    }
    __syncthreads();
    if (grp == 0) {
        const int sl = (gw * 64 + lane) * 4;
#pragma unroll
        for (int nb = 0; nb < 4; nb++)
            o[nb] += *(const v4f*)&oShare[nb * 1024 + sl];
        ls += *(const v4f*)&lsShare[sl];
        float ir[4];
#pragma unroll
        for (int r = 0; r < 4; r++)
            ir[r] = 1.0f / ls[r];
        _Float16* Op = O16 + ((size_t)bh * SS + q0) * 64;
#pragma unroll
        for (int nb = 0; nb < 4; nb++)
#pragma unroll
            for (int r = 0; r < 4; r++)
                Op[(quad * 4 + r) * 64 + 16 * nb + llow] = (_Float16)(o[nb][r] * ir[r]);
    }
}

// ---------------------------------------------------------------------------
// Kernel 3: output projection via MFMA (unchanged).
// ---------------------------------------------------------------------------
__global__ __launch_bounds__(256) void out_kernel(
    const _Float16* __restrict__ O16, const _Float16* __restrict__ WoT,
    const float* __restrict__ bo, float* __restrict__ out)
{
    __shared__ __align__(16) float red[4][16][66];
    const int r0   = blockIdx.x * 16;
    const int wave = threadIdx.x >> 6, lane = threadIdx.x & 63;
    const int llow = lane & 15, quad = lane >> 4;
    const int b = r0 >> 11, s = r0 & 2047;

    v4f acc[4];
#pragma unroll
    for (int cb = 0; cb < 4; cb++) acc[cb] = (v4f){0.f, 0.f, 0.f, 0.f};

#pragma unroll
    for (int i = 0; i < 6; i++) {
        const int kb = wave * 6 + i;                // 0..23
        const int h = kb >> 1, dseg = (kb & 1) * 32;
        v8h af = *(const v8h*)(O16 + ((size_t)(b * HH + h) * SS + s + llow) * 64 + dseg + quad * 8);
#pragma unroll
        for (int cb = 0; cb < 4; cb++) {
            v8h bf = *(const v8h*)(WoT + (size_t)(16 * cb + llow) * 768 + kb * 32 + quad * 8);
            acc[cb] = __builtin_amdgcn_mfma_f32_16x16x32_f16(af, bf, acc[cb], 0, 0, 0);
        }
    }

#pragma unroll
    for (int cb = 0; cb < 4; cb++)
#pragma unroll
        for (int r = 0; r < 4; r++)
            red[wave][quad * 4 + r][16 * cb + llow] = acc[cb][r];
    __syncthreads();

    const int col = threadIdx.x & 63, rr = threadIdx.x >> 6;
    const float bias = bo[col];
    for (int i = rr; i < 16; i += 4) {
        float sum = red[0][i][col] + red[1][i][col] + red[2][i][col] + red[3][i][col] + bias;
        out[(size_t)(r0 + i) * 64 + col] = sum;
    }
}

// ---------------------------------------------------------------------------
extern "C" void kernel_launch(void* const* d_in, const int* in_sizes, int n_in,
                              void* d_out, int out_size, void* d_ws, size_t ws_size,
                              hipStream_t stream)
{
    const float* x  = (const float*)d_in[0];
    const float* Wq = (const float*)d_in[1];
    const float* bq = (const float*)d_in[2];
    const float* Wk = (const float*)d_in[3];
    const float* bk = (const float*)d_in[4];
    const float* Wv = (const float*)d_in[5];
    const float* bv = (const float*)d_in[6];
    const float* Wo = (const float*)d_in[7];
    const float* bo = (const float*)d_in[8];
    float* out = (float*)d_out;

    char* w = (char*)d_ws;
    const size_t MB = 1024 * 1024;
    _Float16*       x16 = (_Float16*)(w);                 // 512 KB
    _Float16*       W16 = (_Float16*)(w + 512 * 1024);    // 288 KB
    _Float16*       WoT = (_Float16*)(w + 832 * 1024);    // 96 KB
    _Float16*       Q16 = (_Float16*)(w + 1 * MB);        // 6 MB each
    _Float16*       K16 = (_Float16*)(w + 7 * MB);
    unsigned short* VT  = (unsigned short*)(w + 13 * MB);
    _Float16*       O16 = (_Float16*)(w + 19 * MB);

    prep_kernel<<<1792, 256, 0, stream>>>(x, Wq, Wk, Wv, Wo, x16, W16, WoT);
    qkv_kernel<<<dim3(64, 36), 256, 0, stream>>>(x16, W16, bq, bk, bv, Q16, K16, VT);
    attn_kernel<<<dim3(32, BB * HH), 512, 0, stream>>>(Q16, K16, VT, O16);
    out_kernel<<<(BB * SS) / 16, 256, 0, stream>>>(O16, WoT, bo, out);
}

// Round 8
// 135.697 us; speedup vs baseline: 1.2682x; 1.0056x over previous
//
#include <hip/hip_runtime.h>
#include <math.h>
#include <type_traits>

#define BB 2
#define SS 2048
#define DD 64
#define HH 12
// Q pre-scaled by 1/ln2 in qkv; exp(s-16) == exp2(s' - 16/ln2)
#define C2FIX 23.083120654223414f

typedef _Float16 v8h __attribute__((ext_vector_type(8)));
typedef short    v8s __attribute__((ext_vector_type(8)));
typedef short    v4s __attribute__((ext_vector_type(4)));
typedef float    v4f __attribute__((ext_vector_type(4)));
typedef unsigned int v2u __attribute__((ext_vector_type(2)));

__device__ __forceinline__ unsigned short f2bf(float f) {
    unsigned u = __float_as_uint(f);
    u += 0x7FFF + ((u >> 16) & 1);          // RTN-even
    return (unsigned short)(u >> 16);
}

__device__ __forceinline__ void async16(const void* g, void* l) {
    __builtin_amdgcn_global_load_lds(
        (const __attribute__((address_space(1))) unsigned int*)g,
        (__attribute__((address_space(3))) unsigned int*)l, 16, 0, 0);
}

// ---------------------------------------------------------------------------
// Kernel 0: prep. x -> x16 fp16; [Wq|Wk|Wv] -> W16 fp16 B-layout [2304][64];
// Wo -> WoT fp16 [64][768].  (exact R15 baseline)
// ---------------------------------------------------------------------------
__global__ __launch_bounds__(256) void prep_kernel(
    const float* __restrict__ x,
    const float* __restrict__ Wq, const float* __restrict__ Wk,
    const float* __restrict__ Wv, const float* __restrict__ Wo,
    _Float16* __restrict__ x16, _Float16* __restrict__ W16,
    _Float16* __restrict__ WoT)
{
    const int idx = blockIdx.x * 256 + threadIdx.x;
    if (idx < 262144) {
        x16[idx] = (_Float16)x[idx];
    } else if (idx < 262144 + 147456) {
        const int t = idx - 262144;
        const int k = t / 2304, c = t % 2304;        // coalesced read over c
        const int mat = c / 768, cc = c % 768;
        const float* W = (mat == 0) ? Wq : (mat == 1) ? Wk : Wv;
        W16[c * 64 + k] = (_Float16)W[k * 768 + cc];
    } else {
        const int e = idx - 262144 - 147456;         // < 49152
        WoT[(e & 63) * 768 + (e >> 6)] = (_Float16)Wo[e];
    }
}

// ---------------------------------------------------------------------------
// Kernel 1: QKV projection via MFMA (exact R12/R15 baseline). Q pre-scaled.
// ---------------------------------------------------------------------------
__global__ __launch_bounds__(256) void qkv_kernel(
    const _Float16* __restrict__ x16, const _Float16* __restrict__ W16,
    const float* __restrict__ bq, const float* __restrict__ bk,
    const float* __restrict__ bv,
    _Float16* __restrict__ Q16, _Float16* __restrict__ K16,
    unsigned short* __restrict__ VT)
{
    const int r0  = blockIdx.x * 64;
    const int c0g = blockIdx.y * 64;
    const int mat = c0g / 768, cc0 = c0g % 768;
    const int h   = cc0 >> 6;
    const int b   = r0 >> 11, s0 = r0 & 2047;

    const int wave = threadIdx.x >> 6, lane = threadIdx.x & 63;
    const int llow = lane & 15, quad = lane >> 4;
    const int rowbase = r0 + 16 * wave;

    const float* bias = (mat == 0) ? bq : (mat == 1) ? bk : bv;

    v8h a0 = *(const v8h*)(x16 + (size_t)(rowbase + llow) * 64 + quad * 8);
    v8h a1 = *(const v8h*)(x16 + (size_t)(rowbase + llow) * 64 + 32 + quad * 8);

    v4f acc[4];
    float bv4[4];
#pragma unroll
    for (int nb = 0; nb < 4; nb++) {
        const int col = c0g + 16 * nb + llow;
        v8h b0 = *(const v8h*)(W16 + (size_t)col * 64 + quad * 8);
        v8h b1 = *(const v8h*)(W16 + (size_t)col * 64 + 32 + quad * 8);
        v4f a = (v4f){0.f, 0.f, 0.f, 0.f};
        a = __builtin_amdgcn_mfma_f32_16x16x32_f16(a0, b0, a, 0, 0, 0);
        a = __builtin_amdgcn_mfma_f32_16x16x32_f16(a1, b1, a, 0, 0, 0);
        acc[nb] = a;
        bv4[nb] = bias[cc0 + 16 * nb + llow];
    }

    const int bh = b * HH + h;
    if (mat == 0) {                                  // Q: pre-scale by 1/ln2
#pragma unroll
        for (int nb = 0; nb < 4; nb++)
#pragma unroll
            for (int r = 0; r < 4; r++) {
                const int s = s0 + 16 * wave + quad * 4 + r;
                Q16[((size_t)bh * SS + s) * 64 + 16 * nb + llow] =
                    (_Float16)((acc[nb][r] + bv4[nb]) * 1.4426950408889634f);
            }
    } else if (mat == 1) {
#pragma unroll
        for (int nb = 0; nb < 4; nb++)
#pragma unroll
            for (int r = 0; r < 4; r++) {
                const int s = s0 + 16 * wave + quad * 4 + r;
                K16[((size_t)bh * SS + s) * 64 + 16 * nb + llow] =
                    (_Float16)(acc[nb][r] + bv4[nb]);
            }
    } else {
#pragma unroll
        for (int nb = 0; nb < 4; nb++) {
            const int d = 16 * nb + llow;
            const int s = s0 + 16 * wave + quad * 4;     // 4 consecutive s
            unsigned short p0 = f2bf(acc[nb][0] + bv4[nb]);
            unsigned short p1 = f2bf(acc[nb][1] + bv4[nb]);
            unsigned short p2 = f2bf(acc[nb][2] + bv4[nb]);
            unsigned short p3 = f2bf(acc[nb][3] + bv4[nb]);
            v2u pk = (v2u){(unsigned)p0 | ((unsigned)p1 << 16),
                           (unsigned)p2 | ((unsigned)p3 << 16)};
            *(v2u*)&VT[((size_t)bh * 64 + d) * SS + s] = pk;
        }
    }
}

// ---------------------------------------------------------------------------
// Kernel 2: MFMA flash attention. R20 = R15 base (4 waves, 64 q-rows,
// dim3(32,24) swizzle — best total 131.2) with ONE change-group: the Pl
// LDS round-trip is ELIMINATED via K=16 PV MFMAs. Layout identity: the
// 16x16x16 A-operand wants A[row=llow][k=4*quad+j], and after swapped
// QK^T lane (llow,quad) holds exactly P[q=llow][key=16cb+4quad+j] =
// sc[cb][j] — the softmax output is ALREADY the A-fragment. So PV =
// 4nb x 4cb mfma_f32_16x16x16bf16_1k with A = in-register packed bf16
// pairs (bit-identical to the old Pl path), B = V^T via b64 swizzled
// LDS reads (issued BEFORE softmax — no P dependency). ls ones-trick
// likewise 4x K=16. Removes per round/wave: 4 ds_write + 2 ds_read_b128
// + the write->read lgkm serialization that sat on the round's critical
// chain (R19 evidence: all pipes <30%, round interval ~4200cy vs ~1000cy
// of work; 811K bank conflicts). LDS 40->32 KB. C layout of K=16 matches
// K=32 (row=4quad+r, col=llow): epilogue, mask, numerics unchanged.
// ---------------------------------------------------------------------------
__global__ __launch_bounds__(256, 4) void attn_kernel(
    const _Float16* __restrict__ Q16, const _Float16* __restrict__ K16,
    const unsigned short* __restrict__ VTg, _Float16* __restrict__ O16)
{
    __shared__ __align__(16) _Float16       Kl[2][64 * 64];   // [key][d], xor-swizzled
    __shared__ __align__(16) unsigned short Vl[2][64 * 64];   // [d][key], xor-swizzled

    const int bh    = blockIdx.y;
    const int qtile = (int)((blockIdx.x + 11 * blockIdx.y) & 31);   // balance swizzle
    const int qBase = qtile * 64;
    const int wave  = threadIdx.x >> 6;
    const int lane  = threadIdx.x & 63;
    const int llow  = lane & 15;
    const int quad  = lane >> 4;
    const int q0    = qBase + 16 * wave;

    const _Float16*       Kp = K16 + (size_t)bh * SS * 64;
    const unsigned short* Vp = VTg + (size_t)bh * 64 * SS;

    const _Float16* Qp = Q16 + ((size_t)bh * SS + q0) * 64;
    v8h qa0 = *(const v8h*)(Qp + llow * 64 + quad * 8);
    v8h qa1 = *(const v8h*)(Qp + llow * 64 + 32 + quad * 8);

    v4f o[4];
    v4f ls = (v4f){0.f, 0.f, 0.f, 0.f};             // row sums via MFMA
    const short one_bf = (short)0x3F80;              // bf16 1.0
    const v4s vones = (v4s){one_bf, one_bf, one_bf, one_bf};
#pragma unroll
    for (int nb = 0; nb < 4; nb++) o[nb] = (v4f){0.f, 0.f, 0.f, 0.f};

    const int nt = qtile + 1;       // 64-key tiles needed
    const int qrow = q0 + llow;
    const int sw = llow & 7;

    // prefetch tile 0 into buf 0 (wave-uniform base + lane*16 dest, DMA rule)
#pragma unroll
    for (int rep = 0; rep < 2; rep++) {
        int c = rep * 256 + threadIdx.x;
        int row = c >> 3, g = (c & 7) ^ (row & 7);
        async16(Kp + (size_t)row * 64 + g * 8, &Kl[0][(rep * 256 + wave * 64) * 8]);
        async16(Vp + (size_t)row * SS + g * 8, &Vl[0][(rep * 256 + wave * 64) * 8]);
    }

    auto tile_body = [&](int t, auto masked_c) {
        constexpr bool MASKED = decltype(masked_c)::value;
        __syncthreads();                 // drains this tile's DMA
        if (t + 1 < nt) {                // prefetch AFTER barrier -> overlaps compute
            const int ktn = (t + 1) * 64, bufn = (t + 1) & 1;
#pragma unroll
            for (int rep = 0; rep < 2; rep++) {
                int c = rep * 256 + threadIdx.x;
                int row = c >> 3, g = (c & 7) ^ (row & 7);
                async16(Kp + (size_t)(ktn + row) * 64 + g * 8,
                        &Kl[bufn][(rep * 256 + wave * 64) * 8]);
                async16(Vp + (size_t)row * SS + ktn + g * 8,
                        &Vl[bufn][(rep * 256 + wave * 64) * 8]);
            }
        }
        const int buf = t & 1, kt = t * 64;

        // ---- S^T = K·Q^T over all 64 keys: 4 col-blocks of 16 ----
        v4f sc[4];
#pragma unroll
        for (int cb = 0; cb < 4; cb++) {
            const int rk = 16 * cb + llow;                       // rk&7 == sw
            v8h k0 = *(const v8h*)&Kl[buf][rk * 64 + ((quad ^ sw)) * 8];
            v8h k1 = *(const v8h*)&Kl[buf][rk * 64 + (((4 + quad) ^ sw)) * 8];
            v4f a2 = (v4f){0.f, 0.f, 0.f, 0.f};
            a2 = __builtin_amdgcn_mfma_f32_16x16x32_f16(k0, qa0, a2, 0, 0, 0);
            a2 = __builtin_amdgcn_mfma_f32_16x16x32_f16(k1, qa1, a2, 0, 0, 0);
            sc[cb] = a2;  // C: col=llow=q-row, row=quad*4+r=key offset
        }

        // ---- V^T b64 frags for K=16 PV: keys 16cb+4quad+{0..3} of row
        //      rv=16nb+llow -> octet (2cb+(quad>>1))^sw, half (quad&1)*4.
        //      No P dependency: issued before softmax, overlaps exp2 chain.
        v4s vvf[4][4];
#pragma unroll
        for (int nb = 0; nb < 4; nb++) {
            const int rv = 16 * nb + llow;                       // rv&7 == sw
#pragma unroll
            for (int cb = 0; cb < 4; cb++)
                vvf[nb][cb] = *(const v4s*)&Vl[buf][rv * 64 +
                                (((2 * cb + (quad >> 1)) ^ sw) * 8) + (quad & 1) * 4];
        }

        // ---- quirky mask + exp2; pack P pairs in-register (A-frags) ----
        v4s pA[4];
#pragma unroll
        for (int cb = 0; cb < 4; cb++) {
            const int kbase = kt + 16 * cb + quad * 4;
            unsigned dw[2];
#pragma unroll
            for (int h2 = 0; h2 < 2; h2++) {
                float pv2[2];
#pragma unroll
                for (int j2 = 0; j2 < 2; j2++) {
                    const int r = h2 * 2 + j2;
                    const float sv = sc[cb][r];
                    const float e  = __builtin_amdgcn_exp2f(sv - C2FIX);
                    float p;
                    if constexpr (MASKED)
                        p = (kbase + r <= qrow && sv != 0.f) ? e : 0.f;
                    else
                        p = (sv != 0.f) ? e : 0.f;   // tril-zero quirk only
                    pv2[j2] = p;
                }
                // bf16-trunc pair pack: one v_perm_b32
                dw[h2] = __builtin_amdgcn_perm(__float_as_uint(pv2[1]),
                                               __float_as_uint(pv2[0]),
                                               0x07060302u);
            }
            v2u pk = (v2u){dw[0], dw[1]};
            pA[cb] = *(const v4s*)&pk;   // A[row=llow][k=4quad+j] = P keys +0..3
        }

        // ---- row sums on the MFMA pipe: ls += P · ones (K=16) ----
#pragma unroll
        for (int cb = 0; cb < 4; cb++)
            ls = __builtin_amdgcn_mfma_f32_16x16x16bf16_1k(pA[cb], vones, ls, 0, 0, 0);

        // ---- PV via K=16 MFMAs: P never left registers ----
#pragma unroll
        for (int nb = 0; nb < 4; nb++)
#pragma unroll
            for (int cb = 0; cb < 4; cb++)
                o[nb] = __builtin_amdgcn_mfma_f32_16x16x16bf16_1k(
                            pA[cb], vvf[nb][cb], o[nb], 0, 0, 0);
    };

    for (int t = 0; t < nt - 1; t++) tile_body(t, std::false_type{});
    tile_body(nt - 1, std::true_type{});            // diagonal tile: causal mask

    // ---- epilogue: ls[r] IS the full row sum for row quad*4+r ----
    float ir[4];
#pragma unroll
    for (int r = 0; r < 4; r++)
        ir[r] = 1.0f / ls[r];
    _Float16* Op = O16 + ((size_t)bh * SS + q0) * 64;
#pragma unroll
    for (int nb = 0; nb < 4; nb++)
#pragma unroll
        for (int r = 0; r < 4; r++)
            Op[(quad * 4 + r) * 64 + 16 * nb + llow] = (_Float16)(o[nb][r] * ir[r]);
}

// ---------------------------------------------------------------------------
// Kernel 3: output projection via MFMA (unchanged).
// ---------------------------------------------------------------------------
__global__ __launch_bounds__(256) void out_kernel(
    const _Float16* __restrict__ O16, const _Float16* __restrict__ WoT,
    const float* __restrict__ bo, float* __restrict__ out)
{
    __shared__ __align__(16) float red[4][16][66];
    const int r0   = blockIdx.x * 16;
    const int wave = threadIdx.x >> 6, lane = threadIdx.x & 63;
    const int llow = lane & 15, quad = lane >> 4;
    const int b = r0 >> 11, s = r0 & 2047;

    v4f acc[4];
#pragma unroll
    for (int cb = 0; cb < 4; cb++) acc[cb] = (v4f){0.f, 0.f, 0.f, 0.f};

#pragma unroll
    for (int i = 0; i < 6; i++) {
        const int kb = wave * 6 + i;                // 0..23
        const int h = kb >> 1, dseg = (kb & 1) * 32;
        v8h af = *(const v8h*)(O16 + ((size_t)(b * HH + h) * SS + s + llow) * 64 + dseg + quad * 8);
#pragma unroll
        for (int cb = 0; cb < 4; cb++) {
            v8h bf = *(const v8h*)(WoT + (size_t)(16 * cb + llow) * 768 + kb * 32 + quad * 8);
            acc[cb] = __builtin_amdgcn_mfma_f32_16x16x32_f16(af, bf, acc[cb], 0, 0, 0);
        }
    }

#pragma unroll
    for (int cb = 0; cb < 4; cb++)
#pragma unroll
        for (int r = 0; r < 4; r++)
            red[wave][quad * 4 + r][16 * cb + llow] = acc[cb][r];
    __syncthreads();

    const int col = threadIdx.x & 63, rr = threadIdx.x >> 6;
    const float bias = bo[col];
    for (int i = rr; i < 16; i += 4) {
        float sum = red[0][i][col] + red[1][i][col] + red[2][i][col] + red[3][i][col] + bias;
        out[(size_t)(r0 + i) * 64 + col] = sum;
    }
}

// ---------------------------------------------------------------------------
extern "C" void kernel_launch(void* const* d_in, const int* in_sizes, int n_in,
                              void* d_out, int out_size, void* d_ws, size_t ws_size,
                              hipStream_t stream)
{
    const float* x  = (const float*)d_in[0];
    const float* Wq = (const float*)d_in[1];
    const float* bq = (const float*)d_in[2];
    const float* Wk = (const float*)d_in[3];
    const float* bk = (const float*)d_in[4];
    const float* Wv = (const float*)d_in[5];
    const float* bv = (const float*)d_in[6];
    const float* Wo = (const float*)d_in[7];
    const float* bo = (const float*)d_in[8];
    float* out = (float*)d_out;

    char* w = (char*)d_ws;
    const size_t MB = 1024 * 1024;
    _Float16*       x16 = (_Float16*)(w);                 // 512 KB
    _Float16*       W16 = (_Float16*)(w + 512 * 1024);    // 288 KB
    _Float16*       WoT = (_Float16*)(w + 832 * 1024);    // 96 KB
    _Float16*       Q16 = (_Float16*)(w + 1 * MB);        // 6 MB each
    _Float16*       K16 = (_Float16*)(w + 7 * MB);
    unsigned short* VT  = (unsigned short*)(w + 13 * MB);
    _Float16*       O16 = (_Float16*)(w + 19 * MB);

    prep_kernel<<<1792, 256, 0, stream>>>(x, Wq, Wk, Wv, Wo, x16, W16, WoT);
    qkv_kernel<<<dim3(64, 36), 256, 0, stream>>>(x16, W16, bq, bk, bv, Q16, K16, VT);
    attn_kernel<<<dim3(32, BB * HH), 256, 0, stream>>>(Q16, K16, VT, O16);
    out_kernel<<<(BB * SS) / 16, 256, 0, stream>>>(O16, WoT, bo, out);
}

// Round 9
// 133.446 us; speedup vs baseline: 1.2896x; 1.0169x over previous
//
#include <hip/hip_runtime.h>
#include <math.h>
#include <type_traits>

#define BB 2
#define SS 2048
#define DD 64
#define HH 12
// Q pre-scaled by 1/ln2 in qkv; exp(s-16) == exp2(s' - 16/ln2)
#define C2FIX 23.083120654223414f

typedef _Float16 v8h __attribute__((ext_vector_type(8)));
typedef short    v8s __attribute__((ext_vector_type(8)));
typedef short    v4s __attribute__((ext_vector_type(4)));
typedef float    v4f __attribute__((ext_vector_type(4)));
typedef unsigned int v2u __attribute__((ext_vector_type(2)));

__device__ __forceinline__ unsigned short f2bf(float f) {
    unsigned u = __float_as_uint(f);
    u += 0x7FFF + ((u >> 16) & 1);          // RTN-even
    return (unsigned short)(u >> 16);
}

__device__ __forceinline__ void async16(const void* g, void* l) {
    __builtin_amdgcn_global_load_lds(
        (const __attribute__((address_space(1))) unsigned int*)g,
        (__attribute__((address_space(3))) unsigned int*)l, 16, 0, 0);
}

// ---------------------------------------------------------------------------
// Kernel 0: prep. x -> x16 fp16; [Wq|Wk|Wv] -> W16 fp16 B-layout [2304][64];
// Wo -> WoT fp16 [64][768].  (exact R15 baseline)
// ---------------------------------------------------------------------------
__global__ __launch_bounds__(256) void prep_kernel(
    const float* __restrict__ x,
    const float* __restrict__ Wq, const float* __restrict__ Wk,
    const float* __restrict__ Wv, const float* __restrict__ Wo,
    _Float16* __restrict__ x16, _Float16* __restrict__ W16,
    _Float16* __restrict__ WoT)
{
    const int idx = blockIdx.x * 256 + threadIdx.x;
    if (idx < 262144) {
        x16[idx] = (_Float16)x[idx];
    } else if (idx < 262144 + 147456) {
        const int t = idx - 262144;
        const int k = t / 2304, c = t % 2304;        // coalesced read over c
        const int mat = c / 768, cc = c % 768;
        const float* W = (mat == 0) ? Wq : (mat == 1) ? Wk : Wv;
        W16[c * 64 + k] = (_Float16)W[k * 768 + cc];
    } else {
        const int e = idx - 262144 - 147456;         // < 49152
        WoT[(e & 63) * 768 + (e >> 6)] = (_Float16)Wo[e];
    }
}

// ---------------------------------------------------------------------------
// Kernel 1: QKV projection via MFMA (exact R12/R15 baseline). Q pre-scaled.
// ---------------------------------------------------------------------------
__global__ __launch_bounds__(256) void qkv_kernel(
    const _Float16* __restrict__ x16, const _Float16* __restrict__ W16,
    const float* __restrict__ bq, const float* __restrict__ bk,
    const float* __restrict__ bv,
    _Float16* __restrict__ Q16, _Float16* __restrict__ K16,
    unsigned short* __restrict__ VT)
{
    const int r0  = blockIdx.x * 64;
    const int c0g = blockIdx.y * 64;
    const int mat = c0g / 768, cc0 = c0g % 768;
    const int h   = cc0 >> 6;
    const int b   = r0 >> 11, s0 = r0 & 2047;

    const int wave = threadIdx.x >> 6, lane = threadIdx.x & 63;
    const int llow = lane & 15, quad = lane >> 4;
    const int rowbase = r0 + 16 * wave;

    const float* bias = (mat == 0) ? bq : (mat == 1) ? bk : bv;

    v8h a0 = *(const v8h*)(x16 + (size_t)(rowbase + llow) * 64 + quad * 8);
    v8h a1 = *(const v8h*)(x16 + (size_t)(rowbase + llow) * 64 + 32 + quad * 8);

    v4f acc[4];
    float bv4[4];
#pragma unroll
    for (int nb = 0; nb < 4; nb++) {
        const int col = c0g + 16 * nb + llow;
        v8h b0 = *(const v8h*)(W16 + (size_t)col * 64 + quad * 8);
        v8h b1 = *(const v8h*)(W16 + (size_t)col * 64 + 32 + quad * 8);
        v4f a = (v4f){0.f, 0.f, 0.f, 0.f};
        a = __builtin_amdgcn_mfma_f32_16x16x32_f16(a0, b0, a, 0, 0, 0);
        a = __builtin_amdgcn_mfma_f32_16x16x32_f16(a1, b1, a, 0, 0, 0);
        acc[nb] = a;
        bv4[nb] = bias[cc0 + 16 * nb + llow];
    }

    const int bh = b * HH + h;
    if (mat == 0) {                                  // Q: pre-scale by 1/ln2
#pragma unroll
        for (int nb = 0; nb < 4; nb++)
#pragma unroll
            for (int r = 0; r < 4; r++) {
                const int s = s0 + 16 * wave + quad * 4 + r;
                Q16[((size_t)bh * SS + s) * 64 + 16 * nb + llow] =
                    (_Float16)((acc[nb][r] + bv4[nb]) * 1.4426950408889634f);
            }
    } else if (mat == 1) {
#pragma unroll
        for (int nb = 0; nb < 4; nb++)
#pragma unroll
            for (int r = 0; r < 4; r++) {
                const int s = s0 + 16 * wave + quad * 4 + r;
                K16[((size_t)bh * SS + s) * 64 + 16 * nb + llow] =
                    (_Float16)(acc[nb][r] + bv4[nb]);
            }
    } else {
#pragma unroll
        for (int nb = 0; nb < 4; nb++) {
            const int d = 16 * nb + llow;
            const int s = s0 + 16 * wave + quad * 4;     // 4 consecutive s
            unsigned short p0 = f2bf(acc[nb][0] + bv4[nb]);
            unsigned short p1 = f2bf(acc[nb][1] + bv4[nb]);
            unsigned short p2 = f2bf(acc[nb][2] + bv4[nb]);
            unsigned short p3 = f2bf(acc[nb][3] + bv4[nb]);
            v2u pk = (v2u){(unsigned)p0 | ((unsigned)p1 << 16),
                           (unsigned)p2 | ((unsigned)p3 << 16)};
            *(v2u*)&VT[((size_t)bh * 64 + d) * SS + s] = pk;
        }
    }
}

// ---------------------------------------------------------------------------
// Kernel 2: MFMA flash attention. R21 = R20 compute internals (in-register
// K=16 PV, no Pl) + T3/T4 pipeline: counted vmcnt + RAW s_barrier + triple
// buffer, 2-tiles-ahead prefetch. R20 diagnosis: attn pinned at ~45us
// across 3 structurally different kernels; round interval ~3375cy vs
// ~800cy of dependent work. Cause (guide, m97/m201): __syncthreads()
// lowers to `s_waitcnt vmcnt(0); s_barrier` — every round drained the
// prefetch issued ~600cy earlier = full exposed HBM latency per round.
// Fix: per round, wait ONLY the current tile's 4 wave-loads
// (s_waitcnt vmcnt(4)); tile t+1's loads stay in flight ACROSS the
// barrier; issue tile t+2 after the barrier. In-flight: prologue issues
// t0,t1 (8); steady state 8; final (masked) round vmcnt(0) (nothing
// behind). Buffer reuse safe: t+2 overwrites buf of t-1, and round-t
// barrier proves all waves left round t-1. Cross-wave LDS visibility:
// each wave drains its own loads BEFORE the barrier (m201 discipline).
// sched_barrier(0) after the barrier pins ds_reads (rule #18).
// LDS 48 KB -> 3 blocks/CU.
// ---------------------------------------------------------------------------
__global__ __launch_bounds__(256, 3) void attn_kernel(
    const _Float16* __restrict__ Q16, const _Float16* __restrict__ K16,
    const unsigned short* __restrict__ VTg, _Float16* __restrict__ O16)
{
    __shared__ __align__(16) _Float16       Kl[3][64 * 64];   // [key][d], xor-swizzled
    __shared__ __align__(16) unsigned short Vl[3][64 * 64];   // [d][key], xor-swizzled

    const int bh    = blockIdx.y;
    const int qtile = (int)((blockIdx.x + 11 * blockIdx.y) & 31);   // balance swizzle
    const int qBase = qtile * 64;
    const int wave  = threadIdx.x >> 6;
    const int lane  = threadIdx.x & 63;
    const int llow  = lane & 15;
    const int quad  = lane >> 4;
    const int q0    = qBase + 16 * wave;

    const _Float16*       Kp = K16 + (size_t)bh * SS * 64;
    const unsigned short* Vp = VTg + (size_t)bh * 64 * SS;

    const _Float16* Qp = Q16 + ((size_t)bh * SS + q0) * 64;
    v8h qa0 = *(const v8h*)(Qp + llow * 64 + quad * 8);
    v8h qa1 = *(const v8h*)(Qp + llow * 64 + 32 + quad * 8);

    v4f o[4];
    v4f ls = (v4f){0.f, 0.f, 0.f, 0.f};             // row sums via MFMA
    const short one_bf = (short)0x3F80;              // bf16 1.0
    const v4s vones = (v4s){one_bf, one_bf, one_bf, one_bf};
#pragma unroll
    for (int nb = 0; nb < 4; nb++) o[nb] = (v4f){0.f, 0.f, 0.f, 0.f};

    const int nt = qtile + 1;       // 64-key tiles needed
    const int qrow = q0 + llow;
    const int sw = llow & 7;

    // stage one 64-key tile into buf b: 4 wave-level global_load_lds each
    // (wave-uniform LDS base + lane*16, DMA rule)
    auto stage = [&](int kt, int b) {
#pragma unroll
        for (int rep = 0; rep < 2; rep++) {
            int c = rep * 256 + threadIdx.x;
            int row = c >> 3, g = (c & 7) ^ (row & 7);
            async16(Kp + (size_t)(kt + row) * 64 + g * 8,
                    &Kl[b][(rep * 256 + wave * 64) * 8]);
            async16(Vp + (size_t)row * SS + kt + g * 8,
                    &Vl[b][(rep * 256 + wave * 64) * 8]);
        }
    };

    // prologue: issue tiles 0 and 1 (4+4 wave-loads in flight)
    stage(0, 0);
    if (nt > 1) stage(64, 1);

    auto round_body = [&](int t, auto masked_c) {
        constexpr bool MASKED = decltype(masked_c)::value;
        // MASKED == final round: only this tile's loads are outstanding.
        if constexpr (MASKED)
            asm volatile("s_waitcnt vmcnt(0)" ::: "memory");
        else
            asm volatile("s_waitcnt vmcnt(4)" ::: "memory");  // tile t done; t+1 in flight
        __builtin_amdgcn_s_barrier();                          // raw: no auto-drain
        __builtin_amdgcn_sched_barrier(0);                     // pin ds_reads below
        if (t + 2 < nt) stage((t + 2) * 64, (t + 2) % 3);      // 2-ahead prefetch
        const int buf = t % 3, kt = t * 64;

        // ---- S^T = K·Q^T over all 64 keys: 4 col-blocks of 16 ----
        v4f sc[4];
#pragma unroll
        for (int cb = 0; cb < 4; cb++) {
            const int rk = 16 * cb + llow;                       // rk&7 == sw
            v8h k0 = *(const v8h*)&Kl[buf][rk * 64 + ((quad ^ sw)) * 8];
            v8h k1 = *(const v8h*)&Kl[buf][rk * 64 + (((4 + quad) ^ sw)) * 8];
            v4f a2 = (v4f){0.f, 0.f, 0.f, 0.f};
            a2 = __builtin_amdgcn_mfma_f32_16x16x32_f16(k0, qa0, a2, 0, 0, 0);
            a2 = __builtin_amdgcn_mfma_f32_16x16x32_f16(k1, qa1, a2, 0, 0, 0);
            sc[cb] = a2;  // C: col=llow=q-row, row=quad*4+r=key offset
        }

        // ---- V^T b64 frags for K=16 PV (no P dependency; overlaps exp2) ----
        v4s vvf[4][4];
#pragma unroll
        for (int nb = 0; nb < 4; nb++) {
            const int rv = 16 * nb + llow;                       // rv&7 == sw
#pragma unroll
            for (int cb = 0; cb < 4; cb++)
                vvf[nb][cb] = *(const v4s*)&Vl[buf][rv * 64 +
                                (((2 * cb + (quad >> 1)) ^ sw) * 8) + (quad & 1) * 4];
        }

        // ---- quirky mask + exp2; pack P pairs in-register (A-frags) ----
        v4s pA[4];
#pragma unroll
        for (int cb = 0; cb < 4; cb++) {
            const int kbase = kt + 16 * cb + quad * 4;
            unsigned dw[2];
#pragma unroll
            for (int h2 = 0; h2 < 2; h2++) {
                float pv2[2];
#pragma unroll
                for (int j2 = 0; j2 < 2; j2++) {
                    const int r = h2 * 2 + j2;
                    const float sv = sc[cb][r];
                    const float e  = __builtin_amdgcn_exp2f(sv - C2FIX);
                    float p;
                    if constexpr (MASKED)
                        p = (kbase + r <= qrow && sv != 0.f) ? e : 0.f;
                    else
                        p = (sv != 0.f) ? e : 0.f;   // tril-zero quirk only
                    pv2[j2] = p;
                }
                // bf16-trunc pair pack: one v_perm_b32
                dw[h2] = __builtin_amdgcn_perm(__float_as_uint(pv2[1]),
                                               __float_as_uint(pv2[0]),
                                               0x07060302u);
            }
            v2u pk = (v2u){dw[0], dw[1]};
            pA[cb] = *(const v4s*)&pk;   // A[row=llow][k=4quad+j] = P keys +0..3
        }

        // ---- row sums on the MFMA pipe: ls += P · ones (K=16) ----
#pragma unroll
        for (int cb = 0; cb < 4; cb++)
            ls = __builtin_amdgcn_mfma_f32_16x16x16bf16_1k(pA[cb], vones, ls, 0, 0, 0);

        // ---- PV via K=16 MFMAs: P never leaves registers ----
#pragma unroll
        for (int nb = 0; nb < 4; nb++)
#pragma unroll
            for (int cb = 0; cb < 4; cb++)
                o[nb] = __builtin_amdgcn_mfma_f32_16x16x16bf16_1k(
                            pA[cb], vvf[nb][cb], o[nb], 0, 0, 0);
    };

    for (int t = 0; t < nt - 1; t++) round_body(t, std::false_type{});
    round_body(nt - 1, std::true_type{});           // diagonal tile: causal mask

    // ---- epilogue: ls[r] IS the full row sum for row quad*4+r ----
    float ir[4];
#pragma unroll
    for (int r = 0; r < 4; r++)
        ir[r] = 1.0f / ls[r];
    _Float16* Op = O16 + ((size_t)bh * SS + q0) * 64;
#pragma unroll
    for (int nb = 0; nb < 4; nb++)
#pragma unroll
        for (int r = 0; r < 4; r++)
            Op[(quad * 4 + r) * 64 + 16 * nb + llow] = (_Float16)(o[nb][r] * ir[r]);
}

// ---------------------------------------------------------------------------
// Kernel 3: output projection via MFMA (unchanged).
// ---------------------------------------------------------------------------
__global__ __launch_bounds__(256) void out_kernel(
    const _Float16* __restrict__ O16, const _Float16* __restrict__ WoT,
    const float* __restrict__ bo, float* __restrict__ out)
{
    __shared__ __align__(16) float red[4][16][66];
    const int r0   = blockIdx.x * 16;
    const int wave = threadIdx.x >> 6, lane = threadIdx.x & 63;
    const int llow = lane & 15, quad = lane >> 4;
    const int b = r0 >> 11, s = r0 & 2047;

    v4f acc[4];
#pragma unroll
    for (int cb = 0; cb < 4; cb++) acc[cb] = (v4f){0.f, 0.f, 0.f, 0.f};

#pragma unroll
    for (int i = 0; i < 6; i++) {
        const int kb = wave * 6 + i;                // 0..23
        const int h = kb >> 1, dseg = (kb & 1) * 32;
        v8h af = *(const v8h*)(O16 + ((size_t)(b * HH + h) * SS + s + llow) * 64 + dseg + quad * 8);
#pragma unroll
        for (int cb = 0; cb < 4; cb++) {
            v8h bf = *(const v8h*)(WoT + (size_t)(16 * cb + llow) * 768 + kb * 32 + quad * 8);
            acc[cb] = __builtin_amdgcn_mfma_f32_16x16x32_f16(af, bf, acc[cb], 0, 0, 0);
        }
    }

#pragma unroll
    for (int cb = 0; cb < 4; cb++)
#pragma unroll
        for (int r = 0; r < 4; r++)
            red[wave][quad * 4 + r][16 * cb + llow] = acc[cb][r];
    __syncthreads();

    const int col = threadIdx.x & 63, rr = threadIdx.x >> 6;
    const float bias = bo[col];
    for (int i = rr; i < 16; i += 4) {
        float sum = red[0][i][col] + red[1][i][col] + red[2][i][col] + red[3][i][col] + bias;
        out[(size_t)(r0 + i) * 64 + col] = sum;
    }
}

// ---------------------------------------------------------------------------
extern "C" void kernel_launch(void* const* d_in, const int* in_sizes, int n_in,
                              void* d_out, int out_size, void* d_ws, size_t ws_size,
                              hipStream_t stream)
{
    const float* x  = (const float*)d_in[0];
    const float* Wq = (const float*)d_in[1];
    const float* bq = (const float*)d_in[2];
    const float* Wk = (const float*)d_in[3];
    const float* bk = (const float*)d_in[4];
    const float* Wv = (const float*)d_in[5];
    const float* bv = (const float*)d_in[6];
    const float* Wo = (const float*)d_in[7];
    const float* bo = (const float*)d_in[8];
    float* out = (float*)d_out;

    char* w = (char*)d_ws;
    const size_t MB = 1024 * 1024;
    _Float16*       x16 = (_Float16*)(w);                 // 512 KB
    _Float16*       W16 = (_Float16*)(w + 512 * 1024);    // 288 KB
    _Float16*       WoT = (_Float16*)(w + 832 * 1024);    // 96 KB
    _Float16*       Q16 = (_Float16*)(w + 1 * MB);        // 6 MB each
    _Float16*       K16 = (_Float16*)(w + 7 * MB);
    unsigned short* VT  = (unsigned short*)(w + 13 * MB);
    _Float16*       O16 = (_Float16*)(w + 19 * MB);

    prep_kernel<<<1792, 256, 0, stream>>>(x, Wq, Wk, Wv, Wo, x16, W16, WoT);
    qkv_kernel<<<dim3(64, 36), 256, 0, stream>>>(x16, W16, bq, bk, bv, Q16, K16, VT);
    attn_kernel<<<dim3(32, BB * HH), 256, 0, stream>>>(Q16, K16, VT, O16);
    out_kernel<<<(BB * SS) / 16, 256, 0, stream>>>(O16, WoT, bo, out);
}